// Round 1
// baseline (226.439 us; speedup 1.0000x reference)
//
#include <hip/hip_runtime.h>
#include <hip/hip_bf16.h>

#define B_ 256
#define N_ 784
#define E_ 6272
#define C_ 32
#define H_ 512
#define NK 25088            // N_*C_
#define S_SPLIT 28          // split-K factor for fc1
#define KSTEPS 28           // MFMA K-steps (of 32) per block: 28*32 = 896; 896*28 = 25088

typedef __attribute__((ext_vector_type(8))) short short8;
typedef __attribute__((ext_vector_type(4))) float f32x4;

__device__ __forceinline__ float elu1(float v) {
  return v > 0.f ? v : (__expf(v) - 1.f);
}

__device__ __forceinline__ unsigned short bf16b(float v) {
  __hip_bfloat16 h = __float2bfloat16(v);
  return *reinterpret_cast<unsigned short*>(&h);
}

// ---------------- K0: build CSR (single block) ----------------
__global__ __launch_bounds__(1024) void k_build_csr(
    const int* __restrict__ erow, const int* __restrict__ ecol,
    const float* __restrict__ eval,
    int* __restrict__ row_ptr, int* __restrict__ col_s, float* __restrict__ val_s) {
  __shared__ int cnt[N_];
  __shared__ int off[N_];
  __shared__ int bufA[1024];
  __shared__ int bufB[1024];
  const int t = threadIdx.x;
  if (t < N_) cnt[t] = 0;
  __syncthreads();
  for (int e = t; e < E_; e += 1024) atomicAdd(&cnt[erow[e]], 1);
  __syncthreads();
  bufA[t] = (t < N_) ? cnt[t] : 0;
  __syncthreads();
  int* src = bufA; int* dst = bufB;
  for (int d = 1; d < 1024; d <<= 1) {
    int v = src[t];
    if (t >= d) v += src[t - d];
    dst[t] = v;
    __syncthreads();
    int* tmp = src; src = dst; dst = tmp;
  }
  if (t < N_) {
    int ex = src[t] - cnt[t];   // exclusive scan
    off[t] = ex;
    row_ptr[t] = ex;
  }
  if (t == 0) row_ptr[N_] = E_;
  __syncthreads();
  for (int e = t; e < E_; e += 1024) {
    int r = erow[e];
    int p = atomicAdd(&off[r], 1);
    col_s[p] = ecol[e];
    val_s[p] = eval[e];
  }
}

// ---------------- K1: spmm1 + W1 + elu -> h1 (bf16) ----------------
__global__ __launch_bounds__(256) void k_gc1(
    const float* __restrict__ x, const int* __restrict__ row_ptr,
    const int* __restrict__ col_s, const float* __restrict__ val_s,
    const float* __restrict__ W1, const float* __restrict__ b1,
    __hip_bfloat16* __restrict__ h1) {
  int idx = blockIdx.x * 256 + threadIdx.x;      // b*784 + n
  int b = idx / N_;
  int n = idx - b * N_;
  const float* xb = x + b * N_;
  int e0 = row_ptr[n], e1 = row_ptr[n + 1];
  float agg = 0.f;
  for (int e = e0; e < e1; ++e)
    agg = fmaf(val_s[e], xb[col_s[e]], agg);
  union { unsigned short u[32]; int4 v[4]; } o;
#pragma unroll
  for (int c = 0; c < C_; ++c)
    o.u[c] = bf16b(elu1(fmaf(agg, W1[c], b1[c])));
  int4* dst = reinterpret_cast<int4*>(h1 + (size_t)idx * C_);
  dst[0] = o.v[0]; dst[1] = o.v[1]; dst[2] = o.v[2]; dst[3] = o.v[3];
}

// ---------------- K2: spmm2 + W2 + elu -> flat (bf16) ----------------
__global__ __launch_bounds__(256) void k_gc2(
    const __hip_bfloat16* __restrict__ h1, const int* __restrict__ row_ptr,
    const int* __restrict__ col_s, const float* __restrict__ val_s,
    const float* __restrict__ W2, const float* __restrict__ b2,
    __hip_bfloat16* __restrict__ flat) {
  __shared__ float w2s[C_][C_ + 1];
  __shared__ float aggs[8][C_ + 1];
  int bi = blockIdx.x;
  int b = bi / 98, chunk = bi - b * 98;
  int t = threadIdx.x;
  for (int i = t; i < C_ * C_; i += 256) w2s[i >> 5][i & 31] = W2[i];
  int nl = t >> 5, c = t & 31;
  int n = chunk * 8 + nl;
  const __hip_bfloat16* hb = h1 + (size_t)b * N_ * C_;
  int e0 = row_ptr[n], e1 = row_ptr[n + 1];
  float agg = 0.f;
  for (int e = e0; e < e1; ++e)
    agg = fmaf(val_s[e], __bfloat162float(hb[col_s[e] * C_ + c]), agg);
  aggs[nl][c] = agg;
  __syncthreads();
  float acc = b2[c];
#pragma unroll
  for (int cc = 0; cc < C_; ++cc)
    acc = fmaf(aggs[nl][cc], w2s[cc][c], acc);
  flat[(size_t)b * NK + n * C_ + c] = __float2bfloat16(elu1(acc));
}

// ---------------- K3: fc1 split-K MFMA GEMM -> partial[S][256][512] ----------------
// grid = S_SPLIT*4; block = 512 (8 waves). Each block: all 256 M-rows x 128 N-cols,
// K-chunk of 896. Wave w owns rows [w*32, w*32+32).
__global__ __launch_bounds__(512) void k_fc1(
    const __hip_bfloat16* __restrict__ flat, const float* __restrict__ Wf1,
    float* __restrict__ partial) {
  __shared__ unsigned short Alds[256][40];   // 32 bf16 + pad to 40 (80B rows, 16B aligned)
  __shared__ unsigned short Blds[128][40];   // transposed Wf1 tile: [n][k]
  int s = blockIdx.x >> 2, nt = blockIdx.x & 3;
  int k0 = s * 896;
  int n0 = nt * 128;
  int tid = threadIdx.x;
  int w = tid >> 6, l = tid & 63;
  int r = l & 15, g = l >> 4;
  f32x4 acc[2][8];
#pragma unroll
  for (int i = 0; i < 2; ++i)
#pragma unroll
    for (int j = 0; j < 8; ++j) acc[i][j] = (f32x4){0.f, 0.f, 0.f, 0.f};
  int am = tid >> 1, ah = tid & 1;       // A staging: row am, 32B half ah
  int bn = tid & 127, bkg = tid >> 7;    // B staging: col bn, k-group bkg (8 k's)
  for (int step = 0; step < KSTEPS; ++step) {
    int kk = k0 + step * 32;
    // A: flat[am][kk + ah*16 .. +16)  (bf16, 32B per thread)
    const int4* asrc = reinterpret_cast<const int4*>(flat + (size_t)am * NK + kk + ah * 16);
    int4 av0 = asrc[0];
    int4 av1 = asrc[1];
    // B: Wf1[kk+bkg*8+i][n0+bn], i=0..7 -> bf16 packed
    union { unsigned short u[8]; int4 v; } bp;
#pragma unroll
    for (int i = 0; i < 8; ++i)
      bp.u[i] = bf16b(Wf1[(size_t)(kk + bkg * 8 + i) * H_ + n0 + bn]);
    int4* adst = reinterpret_cast<int4*>(&Alds[am][ah * 16]);
    adst[0] = av0; adst[1] = av1;
    *reinterpret_cast<int4*>(&Blds[bn][bkg * 8]) = bp.v;
    __syncthreads();
    // A-frag: lane holds A[row = r][k = g*8 + i]; B-frag: B[k = g*8+i][col = r]
    short8 a0 = *reinterpret_cast<const short8*>(&Alds[w * 32 + r][g * 8]);
    short8 a1 = *reinterpret_cast<const short8*>(&Alds[w * 32 + 16 + r][g * 8]);
#pragma unroll
    for (int fn = 0; fn < 8; ++fn) {
      short8 bb = *reinterpret_cast<const short8*>(&Blds[fn * 16 + r][g * 8]);
      acc[0][fn] = __builtin_amdgcn_mfma_f32_16x16x32_bf16(a0, bb, acc[0][fn], 0, 0, 0);
      acc[1][fn] = __builtin_amdgcn_mfma_f32_16x16x32_bf16(a1, bb, acc[1][fn], 0, 0, 0);
    }
    __syncthreads();
  }
  // D layout: col = lane&15 (=r), row = (lane>>4)*4 + q (=g*4+q)
  float* p = partial + (size_t)s * (256 * 512) + n0;
#pragma unroll
  for (int fm = 0; fm < 2; ++fm)
#pragma unroll
    for (int fn = 0; fn < 8; ++fn)
#pragma unroll
      for (int q = 0; q < 4; ++q) {
        int m = w * 32 + fm * 16 + g * 4 + q;
        int n = fn * 16 + r;
        p[m * 512 + n] = acc[fm][fn][q];
      }
}

// ---------------- K4: reduce partials + bias + relu + fc2 + softmax ----------------
__global__ __launch_bounds__(64) void k_head(
    const float* __restrict__ partial, const float* __restrict__ bf1,
    const float* __restrict__ Wf2, const float* __restrict__ bf2,
    float* __restrict__ out) {
  int b = blockIdx.x;
  int t = threadIdx.x;
  float pacc[10];
#pragma unroll
  for (int j = 0; j < 10; ++j) pacc[j] = 0.f;
#pragma unroll
  for (int i = 0; i < 8; ++i) {
    int h = t + i * 64;
    float v = 0.f;
    for (int s = 0; s < S_SPLIT; ++s)
      v += partial[(size_t)s * (256 * 512) + b * 512 + h];
    v += bf1[h];
    v = fmaxf(v, 0.f);
#pragma unroll
    for (int j = 0; j < 10; ++j)
      pacc[j] = fmaf(v, Wf2[h * 10 + j], pacc[j]);
  }
#pragma unroll
  for (int j = 0; j < 10; ++j)
#pragma unroll
    for (int d = 32; d > 0; d >>= 1)
      pacc[j] += __shfl_down(pacc[j], d);
  if (t == 0) {
    float lg[10];
    float m = -1e30f;
#pragma unroll
    for (int j = 0; j < 10; ++j) { lg[j] = pacc[j] + bf2[j]; m = fmaxf(m, lg[j]); }
    float sum = 0.f;
#pragma unroll
    for (int j = 0; j < 10; ++j) { lg[j] = __expf(lg[j] - m); sum += lg[j]; }
    float inv = 1.f / sum;
#pragma unroll
    for (int j = 0; j < 10; ++j) out[b * 10 + j] = lg[j] * inv;
  }
}

extern "C" void kernel_launch(void* const* d_in, const int* in_sizes, int n_in,
                              void* d_out, int out_size, void* d_ws, size_t ws_size,
                              hipStream_t stream) {
  const float* x   = (const float*)d_in[0];
  const int*   erow = (const int*)d_in[1];
  const int*   ecol = (const int*)d_in[2];
  const float* ev  = (const float*)d_in[3];
  const float* W1  = (const float*)d_in[4];
  const float* b1  = (const float*)d_in[5];
  const float* W2  = (const float*)d_in[6];
  const float* b2  = (const float*)d_in[7];
  const float* Wf1 = (const float*)d_in[8];
  const float* bf1 = (const float*)d_in[9];
  const float* Wf2 = (const float*)d_in[10];
  const float* bf2 = (const float*)d_in[11];
  float* out = (float*)d_out;

  // ws layout: [partial (14.68MB) overlaps h1 (12.85MB, dead before K3)] [flat 12.85MB] [CSR]
  char* ws = (char*)d_ws;
  const size_t partial_bytes = (size_t)S_SPLIT * 256 * 512 * 4;   // 14,680,064
  const size_t hbuf_bytes    = (size_t)B_ * N_ * C_ * 2;          // 12,845,056
  __hip_bfloat16* h1   = (__hip_bfloat16*)ws;                     // [0, 12.85MB)
  float*          partial = (float*)ws;                           // [0, 14.68MB) after K2
  __hip_bfloat16* flat = (__hip_bfloat16*)(ws + partial_bytes);
  char* tail = ws + partial_bytes + hbuf_bytes;
  int*   row_ptr = (int*)tail;
  int*   col_s   = (int*)(tail + 3152);           // (785*4 rounded to 16)
  float* val_s   = (float*)(tail + 3152 + E_ * 4);

  hipLaunchKernelGGL(k_build_csr, dim3(1), dim3(1024), 0, stream,
                     erow, ecol, ev, row_ptr, col_s, val_s);
  hipLaunchKernelGGL(k_gc1, dim3((B_ * N_) / 256), dim3(256), 0, stream,
                     x, row_ptr, col_s, val_s, W1, b1, h1);
  hipLaunchKernelGGL(k_gc2, dim3(B_ * 98), dim3(256), 0, stream,
                     h1, row_ptr, col_s, val_s, W2, b2, flat);
  hipLaunchKernelGGL(k_fc1, dim3(S_SPLIT * 4), dim3(512), 0, stream,
                     flat, Wf1, partial);
  hipLaunchKernelGGL(k_head, dim3(B_), dim3(64), 0, stream,
                     partial, bf1, Wf2, bf2, out);
}

// Round 2
// 144.262 us; speedup vs baseline: 1.5696x; 1.5696x over previous
//
#include <hip/hip_runtime.h>
#include <hip/hip_bf16.h>

#define B_ 256
#define N_ 784
#define E_ 6272
#define C_ 32
#define H_ 512
#define NK 25088            // N_*C_
#define S_SPLIT 28          // split-K factor for fc1
#define KCHUNK 896          // 25088 / 28
#define KSTEPS 28           // 896 / 32

typedef __attribute__((ext_vector_type(8))) short short8;
typedef __attribute__((ext_vector_type(4))) float f32x4;

__device__ __forceinline__ float elu1(float v) {
  return v > 0.f ? v : (__expf(v) - 1.f);
}

__device__ __forceinline__ unsigned short bf16b(float v) {
  __hip_bfloat16 h = __float2bfloat16(v);
  return *reinterpret_cast<unsigned short*>(&h);
}

__device__ __forceinline__ unsigned int pk2(float lo, float hi) {
  return (unsigned int)bf16b(lo) | ((unsigned int)bf16b(hi) << 16);
}

// ---------------- K0: build CSR (single block) ----------------
__global__ __launch_bounds__(1024) void k_build_csr(
    const int* __restrict__ erow, const int* __restrict__ ecol,
    const float* __restrict__ eval,
    int* __restrict__ row_ptr, int* __restrict__ col_s, float* __restrict__ val_s) {
  __shared__ int cnt[N_];
  __shared__ int off[N_];
  __shared__ int bufA[1024];
  __shared__ int bufB[1024];
  const int t = threadIdx.x;
  if (t < N_) cnt[t] = 0;
  __syncthreads();
  for (int e = t; e < E_; e += 1024) atomicAdd(&cnt[erow[e]], 1);
  __syncthreads();
  bufA[t] = (t < N_) ? cnt[t] : 0;
  __syncthreads();
  int* src = bufA; int* dst = bufB;
  for (int d = 1; d < 1024; d <<= 1) {
    int v = src[t];
    if (t >= d) v += src[t - d];
    dst[t] = v;
    __syncthreads();
    int* tmp = src; src = dst; dst = tmp;
  }
  if (t < N_) {
    int ex = src[t] - cnt[t];   // exclusive scan
    off[t] = ex;
    row_ptr[t] = ex;
  }
  if (t == 0) row_ptr[N_] = E_;
  __syncthreads();
  for (int e = t; e < E_; e += 1024) {
    int r = erow[e];
    int p = atomicAdd(&off[r], 1);
    col_s[p] = ecol[e];
    val_s[p] = eval[e];
  }
}

// ---------------- K1a: transpose x [B][N] -> xT [N][B] ----------------
__global__ __launch_bounds__(256) void k_xt(
    const float* __restrict__ x, float* __restrict__ xT) {
  __shared__ float tile[32][33];
  int n0 = blockIdx.x * 32, b0 = blockIdx.y * 32;
  int t = threadIdx.x;
  int ni = t & 31, bi = t >> 5;
#pragma unroll
  for (int it = 0; it < 4; ++it) {
    int n = n0 + ni;
    if (n < N_) tile[ni][bi + it * 8] = x[(b0 + bi + it * 8) * N_ + n];
  }
  __syncthreads();
  int bj = t & 31, nj = t >> 5;
#pragma unroll
  for (int it = 0; it < 4; ++it) {
    int n = n0 + nj + it * 8;
    if (n < N_) xT[n * B_ + b0 + bj] = tile[nj + it * 8][bj];
  }
}

// ---------------- K1b: spmm1 -> agg1[n][b] (f32 scalar per node) ----------------
__global__ __launch_bounds__(256) void k_gc1(
    const float* __restrict__ xT, const int* __restrict__ row_ptr,
    const int* __restrict__ col_s, const float* __restrict__ val_s,
    float* __restrict__ agg1) {
  int n = blockIdx.x, t = threadIdx.x;
  int e0 = row_ptr[n], e1 = row_ptr[n + 1];
  float agg = 0.f;
  for (int e = e0; e < e1; ++e)
    agg = fmaf(val_s[e], xT[col_s[e] * B_ + t], agg);
  agg1[n * B_ + t] = agg;
}

// ---------------- K2: spmm2 (h1 recomputed from agg1) + W2 + elu -> flat ----------------
// h1[n][b][c] = elu(agg1[n][b]*W1[c] + b1[c])   (F==1, rank-1 structure)
__global__ __launch_bounds__(256) void k_gc2(
    const float* __restrict__ agg1, const int* __restrict__ row_ptr,
    const int* __restrict__ col_s, const float* __restrict__ val_s,
    const float* __restrict__ W1, const float* __restrict__ b1,
    const float* __restrict__ W2, const float* __restrict__ b2,
    __hip_bfloat16* __restrict__ flat) {
  __shared__ float w2s[C_][C_ + 1];
  int n = blockIdx.x;
  int t = threadIdx.x;          // = batch b
  for (int i = t; i < C_ * C_; i += 256) w2s[i >> 5][i & 31] = W2[i];
  float w1r[C_], b1r[C_];
#pragma unroll
  for (int c = 0; c < C_; ++c) { w1r[c] = W1[c]; b1r[c] = b1[c]; }
  float acc[C_];
#pragma unroll
  for (int c = 0; c < C_; ++c) acc[c] = 0.f;
  int e0 = row_ptr[n], e1 = row_ptr[n + 1];
  __syncthreads();
  for (int e = e0; e < e1; ++e) {
    float val = val_s[e];
    float a = agg1[col_s[e] * B_ + t];
#pragma unroll
    for (int c = 0; c < C_; ++c) {
      float h = fmaf(a, w1r[c], b1r[c]);
      h = elu1(h);
      acc[c] = fmaf(val, h, acc[c]);
    }
  }
  union { unsigned short u[C_]; int4 v[4]; } ob;
#pragma unroll
  for (int c2 = 0; c2 < C_; ++c2) {
    float o = b2[c2];
#pragma unroll
    for (int c = 0; c < C_; ++c)
      o = fmaf(acc[c], w2s[c][c2], o);
    ob.u[c2] = bf16b(elu1(o));
  }
  int4* dst = reinterpret_cast<int4*>(flat + (size_t)t * NK + n * C_);
  dst[0] = ob.v[0]; dst[1] = ob.v[1]; dst[2] = ob.v[2]; dst[3] = ob.v[3];
}

// ---------------- K3: fc1 split-K MFMA GEMM -> partial[S][256][512] ----------------
// grid = S_SPLIT * 8 (2 m-tiles x 4 n-tiles); block = 512 (8 waves).
// Block tile: 128m x 128n, k-chunk 896. Wave w: 32m x 64n sub-tile.
__global__ __launch_bounds__(512) void k_fc1(
    const __hip_bfloat16* __restrict__ flat, const float* __restrict__ Wf1,
    float* __restrict__ partial) {
  __shared__ unsigned short Alds[128][40];   // [m][k], 80B rows (5x16B: conflict-benign)
  __shared__ unsigned short Blds[128][40];   // [n][k] transposed Wf1 tile
  int bid = blockIdx.x;
  int s = bid >> 3, r8 = bid & 7;
  int m0 = (r8 & 1) * 128;
  int n0 = (r8 >> 1) * 128;
  int k0 = s * KCHUNK;
  int tid = threadIdx.x;
  int w = tid >> 6, l = tid & 63;
  int r = l & 15, g = l >> 4;
  int wm = (w & 3) * 32;       // wave m-offset in tile
  int wn = (w >> 2) * 64;      // wave n-offset in tile
  f32x4 acc[2][4];
#pragma unroll
  for (int i = 0; i < 2; ++i)
#pragma unroll
    for (int j = 0; j < 4; ++j) acc[i][j] = (f32x4){0.f, 0.f, 0.f, 0.f};
  int am = tid >> 2, aq = tid & 3;      // A staging: row am, 16B chunk aq
  int bkh = tid >> 5, bnq = tid & 31;   // B staging: k-pair 2*bkh, n-quad bnq*4
  for (int step = 0; step < KSTEPS; ++step) {
    int kk = k0 + step * 32;
    const int4 av = *reinterpret_cast<const int4*>(
        flat + (size_t)(m0 + am) * NK + kk + aq * 8);
    const float4 r0 = *reinterpret_cast<const float4*>(
        Wf1 + (size_t)(kk + 2 * bkh) * H_ + n0 + bnq * 4);
    const float4 r1 = *reinterpret_cast<const float4*>(
        Wf1 + (size_t)(kk + 2 * bkh + 1) * H_ + n0 + bnq * 4);
    *reinterpret_cast<int4*>(&Alds[am][aq * 8]) = av;
    *reinterpret_cast<unsigned int*>(&Blds[bnq * 4 + 0][2 * bkh]) = pk2(r0.x, r1.x);
    *reinterpret_cast<unsigned int*>(&Blds[bnq * 4 + 1][2 * bkh]) = pk2(r0.y, r1.y);
    *reinterpret_cast<unsigned int*>(&Blds[bnq * 4 + 2][2 * bkh]) = pk2(r0.z, r1.z);
    *reinterpret_cast<unsigned int*>(&Blds[bnq * 4 + 3][2 * bkh]) = pk2(r0.w, r1.w);
    __syncthreads();
    short8 a0 = *reinterpret_cast<const short8*>(&Alds[wm + r][g * 8]);
    short8 a1 = *reinterpret_cast<const short8*>(&Alds[wm + 16 + r][g * 8]);
#pragma unroll
    for (int fn = 0; fn < 4; ++fn) {
      short8 bb = *reinterpret_cast<const short8*>(&Blds[wn + fn * 16 + r][g * 8]);
      acc[0][fn] = __builtin_amdgcn_mfma_f32_16x16x32_bf16(a0, bb, acc[0][fn], 0, 0, 0);
      acc[1][fn] = __builtin_amdgcn_mfma_f32_16x16x32_bf16(a1, bb, acc[1][fn], 0, 0, 0);
    }
    __syncthreads();
  }
  // D layout: col = lane&15 (=r), row = g*4 + q
  float* p = partial + (size_t)s * (256 * 512);
#pragma unroll
  for (int fm = 0; fm < 2; ++fm)
#pragma unroll
    for (int fn = 0; fn < 4; ++fn)
#pragma unroll
      for (int q = 0; q < 4; ++q) {
        int m = m0 + wm + fm * 16 + g * 4 + q;
        int n = n0 + wn + fn * 16 + r;
        p[m * 512 + n] = acc[fm][fn][q];
      }
}

// ---------------- K4: reduce partials + bias + relu + fc2 + softmax ----------------
__global__ __launch_bounds__(64) void k_head(
    const float* __restrict__ partial, const float* __restrict__ bf1,
    const float* __restrict__ Wf2, const float* __restrict__ bf2,
    float* __restrict__ out) {
  int b = blockIdx.x;
  int t = threadIdx.x;
  float pacc[10];
#pragma unroll
  for (int j = 0; j < 10; ++j) pacc[j] = 0.f;
#pragma unroll
  for (int i = 0; i < 8; ++i) {
    int h = t + i * 64;
    float v = 0.f;
    for (int s = 0; s < S_SPLIT; ++s)
      v += partial[(size_t)s * (256 * 512) + b * 512 + h];
    v += bf1[h];
    v = fmaxf(v, 0.f);
#pragma unroll
    for (int j = 0; j < 10; ++j)
      pacc[j] = fmaf(v, Wf2[h * 10 + j], pacc[j]);
  }
#pragma unroll
  for (int j = 0; j < 10; ++j)
#pragma unroll
    for (int d = 32; d > 0; d >>= 1)
      pacc[j] += __shfl_down(pacc[j], d);
  if (t == 0) {
    float lg[10];
    float m = -1e30f;
#pragma unroll
    for (int j = 0; j < 10; ++j) { lg[j] = pacc[j] + bf2[j]; m = fmaxf(m, lg[j]); }
    float sum = 0.f;
#pragma unroll
    for (int j = 0; j < 10; ++j) { lg[j] = __expf(lg[j] - m); sum += lg[j]; }
    float inv = 1.f / sum;
#pragma unroll
    for (int j = 0; j < 10; ++j) out[b * 10 + j] = lg[j] * inv;
  }
}

extern "C" void kernel_launch(void* const* d_in, const int* in_sizes, int n_in,
                              void* d_out, int out_size, void* d_ws, size_t ws_size,
                              hipStream_t stream) {
  const float* x    = (const float*)d_in[0];
  const int*   erow = (const int*)d_in[1];
  const int*   ecol = (const int*)d_in[2];
  const float* ev   = (const float*)d_in[3];
  const float* W1   = (const float*)d_in[4];
  const float* b1   = (const float*)d_in[5];
  const float* W2   = (const float*)d_in[6];
  const float* b2   = (const float*)d_in[7];
  const float* Wf1  = (const float*)d_in[8];
  const float* bf1  = (const float*)d_in[9];
  const float* Wf2  = (const float*)d_in[10];
  const float* bf2  = (const float*)d_in[11];
  float* out = (float*)d_out;

  // ws layout (27.6 MB):
  //   [0, 14.68M)      partial  (written by fc1; first 1.6MB doubles as xT+agg1,
  //                              both dead before fc1 runs)
  //   [14.68M, 27.53M) flat bf16
  //   tail             CSR (row_ptr, col_s, val_s)
  char* ws = (char*)d_ws;
  const size_t partial_bytes = (size_t)S_SPLIT * 256 * 512 * 4;   // 14,680,064
  const size_t flat_bytes    = (size_t)B_ * NK * 2;               // 12,845,056
  float* partial = (float*)ws;
  float* xT   = (float*)ws;                          // [0, 802816)
  float* agg1 = (float*)(ws + 802816);               // [802816, 1605632)
  __hip_bfloat16* flat = (__hip_bfloat16*)(ws + partial_bytes);
  char* tail = ws + partial_bytes + flat_bytes;
  int*   row_ptr = (int*)tail;
  int*   col_s   = (int*)(tail + 3152);
  float* val_s   = (float*)(tail + 3152 + E_ * 4);

  hipLaunchKernelGGL(k_build_csr, dim3(1), dim3(1024), 0, stream,
                     erow, ecol, ev, row_ptr, col_s, val_s);
  hipLaunchKernelGGL(k_xt, dim3(25, 8), dim3(256), 0, stream, x, xT);
  hipLaunchKernelGGL(k_gc1, dim3(N_), dim3(256), 0, stream,
                     xT, row_ptr, col_s, val_s, agg1);
  hipLaunchKernelGGL(k_gc2, dim3(N_), dim3(256), 0, stream,
                     agg1, row_ptr, col_s, val_s, W1, b1, W2, b2, flat);
  hipLaunchKernelGGL(k_fc1, dim3(S_SPLIT * 8), dim3(512), 0, stream,
                     flat, Wf1, partial);
  hipLaunchKernelGGL(k_head, dim3(B_), dim3(64), 0, stream,
                     partial, bf1, Wf2, bf2, out);
}

// Round 3
// 131.027 us; speedup vs baseline: 1.7282x; 1.1010x over previous
//
#include <hip/hip_runtime.h>
#include <hip/hip_bf16.h>

#define B_ 256
#define N_ 784
#define E_ 6272
#define C_ 32
#define H_ 512
#define NK 25088            // N_*C_
#define S_SPLIT 28          // split-K factor for fc1
#define KCHUNK 896          // 25088 / 28
#define KSTEPS 28           // 896 / 32

typedef __attribute__((ext_vector_type(8))) short short8;
typedef __attribute__((ext_vector_type(4))) float f32x4;

__device__ __forceinline__ float elu1(float v) {
  return v > 0.f ? v : (__expf(v) - 1.f);
}

__device__ __forceinline__ unsigned short bf16b(float v) {
  __hip_bfloat16 h = __float2bfloat16(v);
  return *reinterpret_cast<unsigned short*>(&h);
}

__device__ __forceinline__ unsigned int pk2(float lo, float hi) {
  return (unsigned int)bf16b(lo) | ((unsigned int)bf16b(hi) << 16);
}

// ---------------- K0: build CSR (single block) ----------------
__global__ __launch_bounds__(1024) void k_build_csr(
    const int* __restrict__ erow, const int* __restrict__ ecol,
    const float* __restrict__ eval,
    int* __restrict__ row_ptr, int* __restrict__ col_s, float* __restrict__ val_s) {
  __shared__ int cnt[N_];
  __shared__ int off[N_];
  __shared__ int bufA[1024];
  __shared__ int bufB[1024];
  const int t = threadIdx.x;
  if (t < N_) cnt[t] = 0;
  __syncthreads();
  for (int e = t; e < E_; e += 1024) atomicAdd(&cnt[erow[e]], 1);
  __syncthreads();
  bufA[t] = (t < N_) ? cnt[t] : 0;
  __syncthreads();
  int* src = bufA; int* dst = bufB;
  for (int d = 1; d < 1024; d <<= 1) {
    int v = src[t];
    if (t >= d) v += src[t - d];
    dst[t] = v;
    __syncthreads();
    int* tmp = src; src = dst; dst = tmp;
  }
  if (t < N_) {
    int ex = src[t] - cnt[t];   // exclusive scan
    off[t] = ex;
    row_ptr[t] = ex;
  }
  if (t == 0) row_ptr[N_] = E_;
  __syncthreads();
  for (int e = t; e < E_; e += 1024) {
    int r = erow[e];
    int p = atomicAdd(&off[r], 1);
    col_s[p] = ecol[e];
    val_s[p] = eval[e];
  }
}

// ---------------- K1a: transpose x [B][N] -> xT [N][B] ----------------
__global__ __launch_bounds__(256) void k_xt(
    const float* __restrict__ x, float* __restrict__ xT) {
  __shared__ float tile[32][33];
  int n0 = blockIdx.x * 32, b0 = blockIdx.y * 32;
  int t = threadIdx.x;
  int ni = t & 31, bi = t >> 5;
#pragma unroll
  for (int it = 0; it < 4; ++it) {
    int n = n0 + ni;
    if (n < N_) tile[ni][bi + it * 8] = x[(b0 + bi + it * 8) * N_ + n];
  }
  __syncthreads();
  int bj = t & 31, nj = t >> 5;
#pragma unroll
  for (int it = 0; it < 4; ++it) {
    int n = n0 + nj + it * 8;
    if (n < N_) xT[n * B_ + b0 + bj] = tile[nj + it * 8][bj];
  }
}

// ---------------- K1b: spmm1 -> agg1[n][b] ----------------
__global__ __launch_bounds__(256) void k_gc1(
    const float* __restrict__ xT, const int* __restrict__ row_ptr,
    const int* __restrict__ col_s, const float* __restrict__ val_s,
    float* __restrict__ agg1) {
  int n = blockIdx.x, t = threadIdx.x;
  int e0 = row_ptr[n], e1 = row_ptr[n + 1];
  float agg = 0.f;
  for (int e = e0; e < e1; ++e)
    agg = fmaf(val_s[e], xT[col_s[e] * B_ + t], agg);
  agg1[n * B_ + t] = agg;
}

// ---------------- K2: spmm2 (h1 recomputed) + W2 + elu -> flat ----------------
// block = (chunk of 8 nodes, batch b); lane c = channel. Coalesced flat writes.
__global__ __launch_bounds__(256) void k_gc2(
    const float* __restrict__ agg1, const int* __restrict__ row_ptr,
    const int* __restrict__ col_s, const float* __restrict__ val_s,
    const float* __restrict__ W1, const float* __restrict__ b1,
    const float* __restrict__ W2, const float* __restrict__ b2,
    __hip_bfloat16* __restrict__ flat) {
  __shared__ float w2s[C_][C_ + 1];
  __shared__ float aggs[8][C_ + 1];
  int chunk = blockIdx.x;        // 0..97
  int b = blockIdx.y;            // 0..255
  int t = threadIdx.x, nl = t >> 5, c = t & 31;
  for (int i = t; i < C_ * C_; i += 256) w2s[i >> 5][i & 31] = W2[i];
  int n = chunk * 8 + nl;
  float w1c = W1[c], b1c = b1[c];
  int e0 = row_ptr[n], e1 = row_ptr[n + 1];
  __syncthreads();
  float acc = 0.f;
  for (int e = e0; e < e1; ++e) {
    float val = val_s[e];
    float a = agg1[col_s[e] * B_ + b];
    acc = fmaf(val, elu1(fmaf(a, w1c, b1c)), acc);
  }
  aggs[nl][c] = acc;
  __syncthreads();
  float o = b2[c];
#pragma unroll
  for (int cc = 0; cc < C_; ++cc)
    o = fmaf(aggs[nl][cc], w2s[cc][c], o);
  flat[(size_t)b * NK + n * C_ + c] = __float2bfloat16(elu1(o));
}

// ---------------- K3: fc1 split-K MFMA GEMM -> partial[S][256][512] ----------------
// BM=256 (all batches), BN=64, k-chunk 896. grid = 8 n-tiles * 28 s = 224 blocks,
// 512 threads (8 waves, 4m x 2n; wave tile 64m x 32n). Double-buffered LDS,
// single barrier per K-step, 2-step-deep register prefetch.
__global__ __launch_bounds__(512) void k_fc1(
    const __hip_bfloat16* __restrict__ flat, const float* __restrict__ Wf1,
    float* __restrict__ partial) {
  __shared__ unsigned short Alds[2][256][40];   // [m][k], 80B rows
  __shared__ unsigned short Blds[2][64][40];    // [n][k]
  int s = blockIdx.x >> 3, nt = blockIdx.x & 7;
  int n0 = nt * 64;
  int k0 = s * KCHUNK;
  int tid = threadIdx.x;
  int w = tid >> 6, l = tid & 63;
  int r = l & 15, g = l >> 4;
  int wm = (w & 3) * 64;
  int wn = (w >> 2) * 32;
  int am = tid >> 1, ah = (tid & 1) * 16;     // A: row am, element-offset ah
  bool doB = tid < 256;
  int bkp = (tid >> 4) & 15, bn4 = (tid & 15) * 4;

  f32x4 acc[4][2];
#pragma unroll
  for (int i = 0; i < 4; ++i)
#pragma unroll
    for (int j = 0; j < 2; ++j) acc[i][j] = (f32x4){0.f, 0.f, 0.f, 0.f};

  int4 aX0, aX1, aY0, aY1;
  float4 bX0, bX1, bY0, bY1;

#define GLOAD_A(step, v0, v1) do {                                            \
    const int4* _p = reinterpret_cast<const int4*>(                           \
        flat + (size_t)am * NK + k0 + (step) * 32 + ah);                      \
    v0 = _p[0]; v1 = _p[1];                                                   \
  } while (0)
#define GLOAD_B(step, r0, r1) do {                                            \
    if (doB) {                                                                \
      const float* _b = Wf1 + (size_t)(k0 + (step) * 32 + 2 * bkp) * H_       \
                        + n0 + bn4;                                           \
      r0 = *reinterpret_cast<const float4*>(_b);                              \
      r1 = *reinterpret_cast<const float4*>(_b + H_);                         \
    }                                                                         \
  } while (0)
#define WRITE_LDS(buf, v0, v1, r0, r1) do {                                   \
    int4* _ad = reinterpret_cast<int4*>(&Alds[buf][am][ah]);                  \
    _ad[0] = v0; _ad[1] = v1;                                                 \
    if (doB) {                                                                \
      *reinterpret_cast<unsigned int*>(&Blds[buf][bn4 + 0][2 * bkp]) = pk2(r0.x, r1.x); \
      *reinterpret_cast<unsigned int*>(&Blds[buf][bn4 + 1][2 * bkp]) = pk2(r0.y, r1.y); \
      *reinterpret_cast<unsigned int*>(&Blds[buf][bn4 + 2][2 * bkp]) = pk2(r0.z, r1.z); \
      *reinterpret_cast<unsigned int*>(&Blds[buf][bn4 + 3][2 * bkp]) = pk2(r0.w, r1.w); \
    }                                                                         \
  } while (0)
#define MFMA_STEP(buf) do {                                                   \
    short8 _a[4];                                                             \
    _Pragma("unroll")                                                         \
    for (int fm = 0; fm < 4; ++fm)                                            \
      _a[fm] = *reinterpret_cast<const short8*>(&Alds[buf][wm + fm * 16 + r][g * 8]); \
    _Pragma("unroll")                                                         \
    for (int fn = 0; fn < 2; ++fn) {                                          \
      short8 _bb = *reinterpret_cast<const short8*>(&Blds[buf][wn + fn * 16 + r][g * 8]); \
      _Pragma("unroll")                                                       \
      for (int fm = 0; fm < 4; ++fm)                                          \
        acc[fm][fn] = __builtin_amdgcn_mfma_f32_16x16x32_bf16(_a[fm], _bb, acc[fm][fn], 0, 0, 0); \
    }                                                                         \
  } while (0)

  // Prologue: fetch steps 0,1; stage step 0 into buf0.
  GLOAD_A(0, aX0, aX1); GLOAD_B(0, bX0, bX1);
  GLOAD_A(1, aY0, aY1); GLOAD_B(1, bY0, bY1);
  WRITE_LDS(0, aX0, aX1, bX0, bX1);
  __syncthreads();

  for (int s2 = 0; s2 < KSTEPS; s2 += 2) {
    // body 1: compute step s2 from buf0; stage step s2+1 (regsY) into buf1;
    //         prefetch step s2+2 into regsX.
    WRITE_LDS(1, aY0, aY1, bY0, bY1);
    if (s2 + 2 < KSTEPS) { GLOAD_A(s2 + 2, aX0, aX1); GLOAD_B(s2 + 2, bX0, bX1); }
    MFMA_STEP(0);
    __syncthreads();
    // body 2: compute step s2+1 from buf1; stage step s2+2 (regsX) into buf0;
    //         prefetch step s2+3 into regsY.
    if (s2 + 2 < KSTEPS) WRITE_LDS(0, aX0, aX1, bX0, bX1);
    if (s2 + 3 < KSTEPS) { GLOAD_A(s2 + 3, aY0, aY1); GLOAD_B(s2 + 3, bY0, bY1); }
    MFMA_STEP(1);
    __syncthreads();
  }

#undef GLOAD_A
#undef GLOAD_B
#undef WRITE_LDS
#undef MFMA_STEP

  // D layout: col = lane&15 (=r), row = g*4 + q
  float* p = partial + (size_t)s * (256 * 512);
#pragma unroll
  for (int fm = 0; fm < 4; ++fm)
#pragma unroll
    for (int fn = 0; fn < 2; ++fn)
#pragma unroll
      for (int q = 0; q < 4; ++q) {
        int m = wm + fm * 16 + g * 4 + q;
        int n = n0 + wn + fn * 16 + r;
        p[m * 512 + n] = acc[fm][fn][q];
      }
}

// ---------------- K4: reduce partials + bias + relu + fc2 + softmax ----------------
// block = batch b, 512 threads (thread t owns hidden unit h=t).
__global__ __launch_bounds__(512) void k_head(
    const float* __restrict__ partial, const float* __restrict__ bf1,
    const float* __restrict__ Wf2, const float* __restrict__ bf2,
    float* __restrict__ out) {
  __shared__ float red[8][12];
  int b = blockIdx.x;
  int t = threadIdx.x;
  float v = bf1[t];
#pragma unroll
  for (int s = 0; s < S_SPLIT; ++s)
    v += partial[(size_t)s * (256 * 512) + b * 512 + t];
  v = fmaxf(v, 0.f);
  float pacc[10];
#pragma unroll
  for (int j = 0; j < 10; ++j) pacc[j] = v * Wf2[t * 10 + j];
#pragma unroll
  for (int j = 0; j < 10; ++j)
#pragma unroll
    for (int d = 32; d > 0; d >>= 1)
      pacc[j] += __shfl_down(pacc[j], d);
  int wv = t >> 6, ln = t & 63;
  if (ln == 0) {
#pragma unroll
    for (int j = 0; j < 10; ++j) red[wv][j] = pacc[j];
  }
  __syncthreads();
  if (t == 0) {
    float lg[10];
    float m = -1e30f;
#pragma unroll
    for (int j = 0; j < 10; ++j) {
      float z = bf2[j];
#pragma unroll
      for (int wq = 0; wq < 8; ++wq) z += red[wq][j];
      lg[j] = z;
      m = fmaxf(m, z);
    }
    float sum = 0.f;
#pragma unroll
    for (int j = 0; j < 10; ++j) { lg[j] = __expf(lg[j] - m); sum += lg[j]; }
    float inv = 1.f / sum;
#pragma unroll
    for (int j = 0; j < 10; ++j) out[b * 10 + j] = lg[j] * inv;
  }
}

extern "C" void kernel_launch(void* const* d_in, const int* in_sizes, int n_in,
                              void* d_out, int out_size, void* d_ws, size_t ws_size,
                              hipStream_t stream) {
  const float* x    = (const float*)d_in[0];
  const int*   erow = (const int*)d_in[1];
  const int*   ecol = (const int*)d_in[2];
  const float* ev   = (const float*)d_in[3];
  const float* W1   = (const float*)d_in[4];
  const float* b1   = (const float*)d_in[5];
  const float* W2   = (const float*)d_in[6];
  const float* b2   = (const float*)d_in[7];
  const float* Wf1  = (const float*)d_in[8];
  const float* bf1  = (const float*)d_in[9];
  const float* Wf2  = (const float*)d_in[10];
  const float* bf2  = (const float*)d_in[11];
  float* out = (float*)d_out;

  // ws layout (27.6 MB):
  //   [0, 14.68M)      partial  (first 1.6MB doubles as xT+agg1, dead before fc1)
  //   [14.68M, 27.53M) flat bf16
  //   tail             CSR (row_ptr, col_s, val_s)
  char* ws = (char*)d_ws;
  const size_t partial_bytes = (size_t)S_SPLIT * 256 * 512 * 4;   // 14,680,064
  const size_t flat_bytes    = (size_t)B_ * NK * 2;               // 12,845,056
  float* partial = (float*)ws;
  float* xT   = (float*)ws;                          // [0, 802816)
  float* agg1 = (float*)(ws + 802816);               // [802816, 1605632)
  __hip_bfloat16* flat = (__hip_bfloat16*)(ws + partial_bytes);
  char* tail = ws + partial_bytes + flat_bytes;
  int*   row_ptr = (int*)tail;
  int*   col_s   = (int*)(tail + 3152);
  float* val_s   = (float*)(tail + 3152 + E_ * 4);

  hipLaunchKernelGGL(k_build_csr, dim3(1), dim3(1024), 0, stream,
                     erow, ecol, ev, row_ptr, col_s, val_s);
  hipLaunchKernelGGL(k_xt, dim3(25, 8), dim3(256), 0, stream, x, xT);
  hipLaunchKernelGGL(k_gc1, dim3(N_), dim3(256), 0, stream,
                     xT, row_ptr, col_s, val_s, agg1);
  hipLaunchKernelGGL(k_gc2, dim3(98, B_), dim3(256), 0, stream,
                     agg1, row_ptr, col_s, val_s, W1, b1, W2, b2, flat);
  hipLaunchKernelGGL(k_fc1, dim3(S_SPLIT * 8), dim3(512), 0, stream,
                     flat, Wf1, partial);
  hipLaunchKernelGGL(k_head, dim3(B_), dim3(512), 0, stream,
                     partial, bf1, Wf2, bf2, out);
}

// Round 4
// 94.166 us; speedup vs baseline: 2.4047x; 1.3914x over previous
//
#include <hip/hip_runtime.h>
#include <hip/hip_bf16.h>

#define B_ 256
#define N_ 784
#define E_ 6272
#define C_ 32
#define H_ 512
#define NK 25088            // N_*C_
#define BC 8192             // B_*C_ (h1 node stride)
#define S_SPLIT 28          // split-K factor for fc1
#define KCHUNK 896          // 25088 / 28
#define KSTEPS 28           // 896 / 32

typedef __attribute__((ext_vector_type(8))) short short8;
typedef __attribute__((ext_vector_type(4))) float f32x4;

__device__ __forceinline__ float elu1(float v) {
  return v > 0.f ? v : (__expf(v) - 1.f);
}

__device__ __forceinline__ unsigned short bf16b(float v) {
  __hip_bfloat16 h = __float2bfloat16(v);
  return *reinterpret_cast<unsigned short*>(&h);
}

__device__ __forceinline__ unsigned int pk2(float lo, float hi) {
  return (unsigned int)bf16b(lo) | ((unsigned int)bf16b(hi) << 16);
}

// unpack u32 (2 bf16) and accumulate val*h into a0,a1
__device__ __forceinline__ void acc2(unsigned u, float val, float& a0, float& a1) {
  float lo = __uint_as_float(u << 16);
  float hi = __uint_as_float(u & 0xffff0000u);
  a0 = fmaf(val, lo, a0);
  a1 = fmaf(val, hi, a1);
}

// ---------------- K0: build CSR (single block) ----------------
__global__ __launch_bounds__(1024) void k_build_csr(
    const int* __restrict__ erow, const int* __restrict__ ecol,
    const float* __restrict__ eval,
    int* __restrict__ row_ptr, int* __restrict__ col_s, float* __restrict__ val_s) {
  __shared__ int cnt[N_];
  __shared__ int off[N_];
  __shared__ int bufA[1024];
  __shared__ int bufB[1024];
  const int t = threadIdx.x;
  if (t < N_) cnt[t] = 0;
  __syncthreads();
  for (int e = t; e < E_; e += 1024) atomicAdd(&cnt[erow[e]], 1);
  __syncthreads();
  bufA[t] = (t < N_) ? cnt[t] : 0;
  __syncthreads();
  int* src = bufA; int* dst = bufB;
  for (int d = 1; d < 1024; d <<= 1) {
    int v = src[t];
    if (t >= d) v += src[t - d];
    dst[t] = v;
    __syncthreads();
    int* tmp = src; src = dst; dst = tmp;
  }
  if (t < N_) {
    int ex = src[t] - cnt[t];   // exclusive scan
    off[t] = ex;
    row_ptr[t] = ex;
  }
  if (t == 0) row_ptr[N_] = E_;
  __syncthreads();
  for (int e = t; e < E_; e += 1024) {
    int r = erow[e];
    int p = atomicAdd(&off[r], 1);
    col_s[p] = ecol[e];
    val_s[p] = eval[e];
  }
}

// ---------------- K1a: transpose x [B][N] -> xT [N][B] ----------------
__global__ __launch_bounds__(256) void k_xt(
    const float* __restrict__ x, float* __restrict__ xT) {
  __shared__ float tile[32][33];
  int n0 = blockIdx.x * 32, b0 = blockIdx.y * 32;
  int t = threadIdx.x;
  int ni = t & 31, bi = t >> 5;
#pragma unroll
  for (int it = 0; it < 4; ++it) {
    int n = n0 + ni;
    if (n < N_) tile[ni][bi + it * 8] = x[(b0 + bi + it * 8) * N_ + n];
  }
  __syncthreads();
  int bj = t & 31, nj = t >> 5;
#pragma unroll
  for (int it = 0; it < 4; ++it) {
    int n = n0 + nj + it * 8;
    if (n < N_) xT[n * B_ + b0 + bj] = tile[nj + it * 8][bj];
  }
}

// ---------------- K1b: spmm1 + W1 + elu -> h1[n][b*32+c] (bf16, node-major) ----
__global__ __launch_bounds__(256) void k_gc1(
    const float* __restrict__ xT, const int* __restrict__ row_ptr,
    const int* __restrict__ col_s, const float* __restrict__ val_s,
    const float* __restrict__ W1, const float* __restrict__ b1,
    __hip_bfloat16* __restrict__ h1) {
  __shared__ int lc[64];
  __shared__ float lv[64];
  int n = blockIdx.x, t = threadIdx.x;
  int e0 = row_ptr[n], deg = row_ptr[n + 1] - e0;
  float agg = 0.f;
  for (int base = 0; base < deg; base += 64) {
    int m = min(64, deg - base);
    __syncthreads();
    if (t < m) { lc[t] = col_s[e0 + base + t]; lv[t] = val_s[e0 + base + t]; }
    __syncthreads();
    for (int e = 0; e < m; ++e)
      agg = fmaf(lv[e], xT[lc[e] * B_ + t], agg);
  }
  union { unsigned int u[16]; uint4 v[4]; } ob;
#pragma unroll
  for (int c = 0; c < C_; c += 2) {
    float o0 = elu1(fmaf(agg, W1[c], b1[c]));
    float o1 = elu1(fmaf(agg, W1[c + 1], b1[c + 1]));
    ob.u[c >> 1] = pk2(o0, o1);
  }
  uint4* dst = reinterpret_cast<uint4*>(h1 + (size_t)n * BC + t * C_);
#pragma unroll
  for (int j = 0; j < 4; ++j) dst[j] = ob.v[j];
}

// ---------------- K2: spmm2 (wide gather) + W2 + elu -> flat ----------------
// block = node n; thread t = batch b. Per edge: 64B contiguous load per thread
// (wave reads 4KB contiguous). W2 applied in-register f32 (uniform s_loads).
__global__ __launch_bounds__(256) void k_gc2(
    const __hip_bfloat16* __restrict__ h1, const int* __restrict__ row_ptr,
    const int* __restrict__ col_s, const float* __restrict__ val_s,
    const float* __restrict__ W2, const float* __restrict__ b2,
    __hip_bfloat16* __restrict__ flat) {
  __shared__ int lc[64];
  __shared__ float lv[64];
  int n = blockIdx.x, t = threadIdx.x;
  int e0 = row_ptr[n], deg = row_ptr[n + 1] - e0;
  float acc[C_];
#pragma unroll
  for (int c = 0; c < C_; ++c) acc[c] = 0.f;
  for (int base = 0; base < deg; base += 64) {
    int m = min(64, deg - base);
    __syncthreads();
    if (t < m) { lc[t] = col_s[e0 + base + t]; lv[t] = val_s[e0 + base + t]; }
    __syncthreads();
    for (int e = 0; e < m; ++e) {
      float val = lv[e];
      const uint4* hp = reinterpret_cast<const uint4*>(
          h1 + (size_t)lc[e] * BC + t * C_);
#pragma unroll
      for (int j = 0; j < 4; ++j) {
        uint4 v = hp[j];
        acc2(v.x, val, acc[j * 8 + 0], acc[j * 8 + 1]);
        acc2(v.y, val, acc[j * 8 + 2], acc[j * 8 + 3]);
        acc2(v.z, val, acc[j * 8 + 4], acc[j * 8 + 5]);
        acc2(v.w, val, acc[j * 8 + 6], acc[j * 8 + 7]);
      }
    }
  }
  // W2 apply (f32, W2/b2 uniform -> scalar loads overlap VALU)
  union { unsigned int u[16]; uint4 v[4]; } ob;
#pragma unroll
  for (int c2 = 0; c2 < C_; c2 += 2) {
    float o0 = b2[c2], o1 = b2[c2 + 1];
#pragma unroll
    for (int c = 0; c < C_; ++c) {
      o0 = fmaf(acc[c], W2[c * C_ + c2], o0);
      o1 = fmaf(acc[c], W2[c * C_ + c2 + 1], o1);
    }
    ob.u[c2 >> 1] = pk2(elu1(o0), elu1(o1));
  }
  uint4* dst = reinterpret_cast<uint4*>(flat + (size_t)t * NK + n * C_);
#pragma unroll
  for (int j = 0; j < 4; ++j) dst[j] = ob.v[j];
}

// ---------------- K3: fc1 split-K MFMA GEMM -> partial[S][256][512] ----------------
// BM=256 (all batches), BN=64, k-chunk 896. grid = 8 n-tiles * 28 s = 224 blocks,
// 512 threads (8 waves, 4m x 2n; wave tile 64m x 32n). Double-buffered LDS,
// single barrier per K-step, 2-step-deep register prefetch.
__global__ __launch_bounds__(512) void k_fc1(
    const __hip_bfloat16* __restrict__ flat, const float* __restrict__ Wf1,
    float* __restrict__ partial) {
  __shared__ unsigned short Alds[2][256][40];   // [m][k], 80B rows
  __shared__ unsigned short Blds[2][64][40];    // [n][k]
  int s = blockIdx.x >> 3, nt = blockIdx.x & 7;
  int n0 = nt * 64;
  int k0 = s * KCHUNK;
  int tid = threadIdx.x;
  int w = tid >> 6, l = tid & 63;
  int r = l & 15, g = l >> 4;
  int wm = (w & 3) * 64;
  int wn = (w >> 2) * 32;
  int am = tid >> 1, ah = (tid & 1) * 16;     // A: row am, element-offset ah
  bool doB = tid < 256;
  int bkp = (tid >> 4) & 15, bn4 = (tid & 15) * 4;

  f32x4 acc[4][2];
#pragma unroll
  for (int i = 0; i < 4; ++i)
#pragma unroll
    for (int j = 0; j < 2; ++j) acc[i][j] = (f32x4){0.f, 0.f, 0.f, 0.f};

  int4 aX0, aX1, aY0, aY1;
  float4 bX0, bX1, bY0, bY1;

#define GLOAD_A(step, v0, v1) do {                                            \
    const int4* _p = reinterpret_cast<const int4*>(                           \
        flat + (size_t)am * NK + k0 + (step) * 32 + ah);                      \
    v0 = _p[0]; v1 = _p[1];                                                   \
  } while (0)
#define GLOAD_B(step, r0, r1) do {                                            \
    if (doB) {                                                                \
      const float* _b = Wf1 + (size_t)(k0 + (step) * 32 + 2 * bkp) * H_       \
                        + n0 + bn4;                                           \
      r0 = *reinterpret_cast<const float4*>(_b);                              \
      r1 = *reinterpret_cast<const float4*>(_b + H_);                         \
    }                                                                         \
  } while (0)
#define WRITE_LDS(buf, v0, v1, r0, r1) do {                                   \
    int4* _ad = reinterpret_cast<int4*>(&Alds[buf][am][ah]);                  \
    _ad[0] = v0; _ad[1] = v1;                                                 \
    if (doB) {                                                                \
      *reinterpret_cast<unsigned int*>(&Blds[buf][bn4 + 0][2 * bkp]) = pk2(r0.x, r1.x); \
      *reinterpret_cast<unsigned int*>(&Blds[buf][bn4 + 1][2 * bkp]) = pk2(r0.y, r1.y); \
      *reinterpret_cast<unsigned int*>(&Blds[buf][bn4 + 2][2 * bkp]) = pk2(r0.z, r1.z); \
      *reinterpret_cast<unsigned int*>(&Blds[buf][bn4 + 3][2 * bkp]) = pk2(r0.w, r1.w); \
    }                                                                         \
  } while (0)
#define MFMA_STEP(buf) do {                                                   \
    short8 _a[4];                                                             \
    _Pragma("unroll")                                                         \
    for (int fm = 0; fm < 4; ++fm)                                            \
      _a[fm] = *reinterpret_cast<const short8*>(&Alds[buf][wm + fm * 16 + r][g * 8]); \
    _Pragma("unroll")                                                         \
    for (int fn = 0; fn < 2; ++fn) {                                          \
      short8 _bb = *reinterpret_cast<const short8*>(&Blds[buf][wn + fn * 16 + r][g * 8]); \
      _Pragma("unroll")                                                       \
      for (int fm = 0; fm < 4; ++fm)                                          \
        acc[fm][fn] = __builtin_amdgcn_mfma_f32_16x16x32_bf16(_a[fm], _bb, acc[fm][fn], 0, 0, 0); \
    }                                                                         \
  } while (0)

  GLOAD_A(0, aX0, aX1); GLOAD_B(0, bX0, bX1);
  GLOAD_A(1, aY0, aY1); GLOAD_B(1, bY0, bY1);
  WRITE_LDS(0, aX0, aX1, bX0, bX1);
  __syncthreads();

  for (int s2 = 0; s2 < KSTEPS; s2 += 2) {
    WRITE_LDS(1, aY0, aY1, bY0, bY1);
    if (s2 + 2 < KSTEPS) { GLOAD_A(s2 + 2, aX0, aX1); GLOAD_B(s2 + 2, bX0, bX1); }
    MFMA_STEP(0);
    __syncthreads();
    if (s2 + 2 < KSTEPS) WRITE_LDS(0, aX0, aX1, bX0, bX1);
    if (s2 + 3 < KSTEPS) { GLOAD_A(s2 + 3, aY0, aY1); GLOAD_B(s2 + 3, bY0, bY1); }
    MFMA_STEP(1);
    __syncthreads();
  }

#undef GLOAD_A
#undef GLOAD_B
#undef WRITE_LDS
#undef MFMA_STEP

  float* p = partial + (size_t)s * (256 * 512);
#pragma unroll
  for (int fm = 0; fm < 4; ++fm)
#pragma unroll
    for (int fn = 0; fn < 2; ++fn)
#pragma unroll
      for (int q = 0; q < 4; ++q) {
        int m = wm + fm * 16 + g * 4 + q;
        int n = n0 + wn + fn * 16 + r;
        p[m * 512 + n] = acc[fm][fn][q];
      }
}

// ---------------- K4: reduce partials + bias + relu + fc2 + softmax ----------------
__global__ __launch_bounds__(512) void k_head(
    const float* __restrict__ partial, const float* __restrict__ bf1,
    const float* __restrict__ Wf2, const float* __restrict__ bf2,
    float* __restrict__ out) {
  __shared__ float red[8][12];
  int b = blockIdx.x;
  int t = threadIdx.x;
  float v = bf1[t];
#pragma unroll
  for (int s = 0; s < S_SPLIT; ++s)
    v += partial[(size_t)s * (256 * 512) + b * 512 + t];
  v = fmaxf(v, 0.f);
  float pacc[10];
#pragma unroll
  for (int j = 0; j < 10; ++j) pacc[j] = v * Wf2[t * 10 + j];
#pragma unroll
  for (int j = 0; j < 10; ++j)
#pragma unroll
    for (int d = 32; d > 0; d >>= 1)
      pacc[j] += __shfl_down(pacc[j], d);
  int wv = t >> 6, ln = t & 63;
  if (ln == 0) {
#pragma unroll
    for (int j = 0; j < 10; ++j) red[wv][j] = pacc[j];
  }
  __syncthreads();
  if (t == 0) {
    float lg[10];
    float m = -1e30f;
#pragma unroll
    for (int j = 0; j < 10; ++j) {
      float z = bf2[j];
#pragma unroll
      for (int wq = 0; wq < 8; ++wq) z += red[wq][j];
      lg[j] = z;
      m = fmaxf(m, z);
    }
    float sum = 0.f;
#pragma unroll
    for (int j = 0; j < 10; ++j) { lg[j] = __expf(lg[j] - m); sum += lg[j]; }
    float inv = 1.f / sum;
#pragma unroll
    for (int j = 0; j < 10; ++j) out[b * 10 + j] = lg[j] * inv;
  }
}

extern "C" void kernel_launch(void* const* d_in, const int* in_sizes, int n_in,
                              void* d_out, int out_size, void* d_ws, size_t ws_size,
                              hipStream_t stream) {
  const float* x    = (const float*)d_in[0];
  const int*   erow = (const int*)d_in[1];
  const int*   ecol = (const int*)d_in[2];
  const float* ev   = (const float*)d_in[3];
  const float* W1   = (const float*)d_in[4];
  const float* b1   = (const float*)d_in[5];
  const float* W2   = (const float*)d_in[6];
  const float* b2   = (const float*)d_in[7];
  const float* Wf1  = (const float*)d_in[8];
  const float* bf1  = (const float*)d_in[9];
  const float* Wf2  = (const float*)d_in[10];
  const float* bf2  = (const float*)d_in[11];
  float* out = (float*)d_out;

  // ws layout (27.6 MB):
  //   [0, 0.80M)        xT f32            (dead after gc1)
  //   [0.80M, 13.65M)   h1 bf16 node-major (dead after gc2)
  //   [0, 14.68M)       partial           (fc1 writes after h1/xT dead)
  //   [14.68M, 27.53M)  flat bf16
  //   tail              CSR (row_ptr, col_s, val_s)
  char* ws = (char*)d_ws;
  const size_t partial_bytes = (size_t)S_SPLIT * 256 * 512 * 4;   // 14,680,064
  const size_t flat_bytes    = (size_t)B_ * NK * 2;               // 12,845,056
  float* partial = (float*)ws;
  float* xT = (float*)ws;                                  // [0, 802816)
  __hip_bfloat16* h1 = (__hip_bfloat16*)(ws + 802816);     // 12.85 MB
  __hip_bfloat16* flat = (__hip_bfloat16*)(ws + partial_bytes);
  char* tail = ws + partial_bytes + flat_bytes;
  int*   row_ptr = (int*)tail;
  int*   col_s   = (int*)(tail + 3152);
  float* val_s   = (float*)(tail + 3152 + E_ * 4);

  hipLaunchKernelGGL(k_build_csr, dim3(1), dim3(1024), 0, stream,
                     erow, ecol, ev, row_ptr, col_s, val_s);
  hipLaunchKernelGGL(k_xt, dim3(25, 8), dim3(256), 0, stream, x, xT);
  hipLaunchKernelGGL(k_gc1, dim3(N_), dim3(256), 0, stream,
                     xT, row_ptr, col_s, val_s, W1, b1, h1);
  hipLaunchKernelGGL(k_gc2, dim3(N_), dim3(256), 0, stream,
                     h1, row_ptr, col_s, val_s, W2, b2, flat);
  hipLaunchKernelGGL(k_fc1, dim3(S_SPLIT * 8), dim3(512), 0, stream,
                     flat, Wf1, partial);
  hipLaunchKernelGGL(k_head, dim3(B_), dim3(512), 0, stream,
                     partial, bf1, Wf2, bf2, out);
}